// Round 2
// baseline (387.447 us; speedup 1.0000x reference)
//
#include <hip/hip_runtime.h>
#include <math.h>

#define NN 1024     // entities
#define HD 128      // hidden dim
#define NH 8        // heads
#define CH 16       // dim per head
#define NLAYERS 3

#define ST 1032     // s_tile row stride in floats: 1032 % 32 == 8 -> exact 2-way LDS aliasing (free)

// ---------------- K1: a = x@W1[:128], b = x@W1[128:] + b1 ----------------
__global__ __launch_bounds__(256) void k_edge_ab(
        const float* __restrict__ x, const float* __restrict__ W1,
        const float* __restrict__ b1, float* __restrict__ a, float* __restrict__ b) {
    __shared__ float xr[HD];
    const int row = blockIdx.x, t = threadIdx.x;
    if (t < HD) xr[t] = x[row * HD + t];
    __syncthreads();
    const int c = t & 127;
    const int half = t >> 7;                 // 0 -> a, 1 -> b
    const float* w = W1 + half * HD * HD + c;
    float acc = half ? b1[c] : 0.f;          // fold b1 into b
    #pragma unroll 8
    for (int kk = 0; kk < HD; ++kk) acc = fmaf(xr[kk], w[kk * HD], acc);
    (half ? b : a)[row * HD + c] = acc;
}

// ---------------- K2: wm[t][s] = sign(mask) * sigmoid(logit[s][t]) ----------------
// logit[s][t] = sum_h relu(a[s][h] + bb[t][h]) * W2[h] + b2   (bb already includes b1)
__global__ __launch_bounds__(256) void k_edge_w(
        const float* __restrict__ a, const float* __restrict__ bb,
        const float* __restrict__ W2, const float* __restrict__ b2,
        float* __restrict__ wm) {
    __shared__ float al[32][HD + 1];   // +1 pad: lanes s=0..31 read al[s][h] -> distinct banks
    __shared__ float bl[16][HD];       // broadcast reads
    __shared__ float w2[HD];
    const int t = threadIdx.x;
    const int s0 = blockIdx.x * 32, t0 = blockIdx.y * 16;
    for (int i = t; i < 32 * HD; i += 256) al[i >> 7][i & 127] = a[(s0 + (i >> 7)) * HD + (i & 127)];
    for (int i = t; i < 16 * HD; i += 256) bl[i >> 7][i & 127] = bb[(t0 + (i >> 7)) * HD + (i & 127)];
    if (t < HD) w2[t] = W2[t];
    __syncthreads();
    const int s = t & 31, tt = t >> 5;      // each thread: source s, targets {tt, tt+8}
    float acc0 = 0.f, acc1 = 0.f;
    #pragma unroll 4
    for (int h = 0; h < HD; ++h) {
        const float av = al[s][h], wv = w2[h];
        acc0 = fmaf(fmaxf(av + bl[tt][h],     0.f), wv, acc0);
        acc1 = fmaf(fmaxf(av + bl[tt + 8][h], 0.f), wv, acc1);
    }
    const float bias = b2[0];
    const float l0 = acc0 + bias, l1 = acc1 + bias;
    const float w0 = 1.f / (1.f + __expf(-l0));
    const float w1 = 1.f / (1.f + __expf(-l1));
    wm[(t0 + tt    ) * NN + s0 + s] = (l0 > 0.f) ? w0 : -w0;   // sign encodes mask
    wm[(t0 + tt + 8) * NN + s0 + s] = (l1 > 0.f) ? w1 : -w1;
}

// ---------------- K3: per-layer projections q,k (in [h][n][c]), v (TRANSPOSED [h][c][n]) + skip ----------------
__global__ __launch_bounds__(256) void k_proj(
        const float* __restrict__ x,
        const float* __restrict__ Wq, const float* __restrict__ bq,
        const float* __restrict__ Wk, const float* __restrict__ bk,
        const float* __restrict__ Wv, const float* __restrict__ bv,
        const float* __restrict__ Wsk, const float* __restrict__ bsk,
        float* __restrict__ q, float* __restrict__ k,
        float* __restrict__ v, float* __restrict__ skip) {
    __shared__ float xr[HD];
    const int row = blockIdx.x, t = threadIdx.x;
    if (t < HD) xr[t] = x[row * HD + t];
    __syncthreads();
    const int c = t & 127;
    const bool lo = t < 128;                   // lo: q&k columns, hi: v&skip columns
    const float* WA = lo ? Wq : Wv;
    const float* WB = lo ? Wk : Wsk;
    float a0 = lo ? bq[c] : bv[c];
    float a1 = lo ? bk[c] : bsk[c];
    #pragma unroll 8
    for (int kk = 0; kk < HD; ++kk) {
        const float xv = xr[kk];
        a0 = fmaf(xv, WA[kk * HD + c], a0);
        a1 = fmaf(xv, WB[kk * HD + c], a1);
    }
    if (lo) {
        const int hnc = (c >> 4) * (NN * CH) + row * CH + (c & 15);
        q[hnc] = a0; k[hnc] = a1;
    } else {
        v[(c >> 4) * (NN * CH) + (c & 15) * NN + row] = a0;   // v_t[h][ch][n]
        skip[row * HD + c] = a1;
    }
}

// ---------------- K4: fused attention for one (head, 16-target tile); x updated in place ----------------
__global__ __launch_bounds__(256) void k_attn(
        const float* __restrict__ q, const float* __restrict__ k,
        const float* __restrict__ v, const float* __restrict__ skip,
        const float* __restrict__ wm, const float* __restrict__ We,
        float* __restrict__ x) {
    __shared__ float s_tile[16][ST];   // ~66 KB -> 2 blocks/CU
    __shared__ float q_l[16][CH];      // q * 0.25 (scale folded)
    __shared__ float we_l[CH];
    __shared__ float qwe_l[16];
    const int h  = blockIdx.x;
    const int i0 = blockIdx.y * 16;
    const int t  = threadIdx.x;
    {
        const int i = t >> 4, c = t & 15;
        q_l[i][c] = q[h * (NN * CH) + (i0 + i) * CH + c] * 0.25f;
        if (t < CH) we_l[t] = We[h * CH + t];
    }
    __syncthreads();
    if (t < 16) {
        float sv = 0.f;
        #pragma unroll
        for (int c = 0; c < CH; ++c) sv = fmaf(q_l[t][c], we_l[c], sv);
        qwe_l[t] = sv;                 // already carries the 0.25 scale
    }
    __syncthreads();

    // phase 1: logits. thread t handles j = t + 256*rep for all 16 targets.
    const float* kh = k + h * (NN * CH);
    for (int rep = 0; rep < 4; ++rep) {
        const int j = t + rep * 256;
        const float4* kp = (const float4*)(kh + j * CH);
        const float4 ka = kp[0], kb = kp[1], kc = kp[2], kd = kp[3];
        float kr[CH] = {ka.x, ka.y, ka.z, ka.w, kb.x, kb.y, kb.z, kb.w,
                        kc.x, kc.y, kc.z, kc.w, kd.x, kd.y, kd.z, kd.w};
        #pragma unroll
        for (int i = 0; i < 16; ++i) {
            float dot = 0.f;
            #pragma unroll
            for (int c = 0; c < CH; ++c) dot = fmaf(q_l[i][c], kr[c], dot);
            const float wv = wm[(i0 + i) * NN + j];          // sign = mask
            const float sv = dot + qwe_l[i] * fabsf(wv);
            s_tile[i][j] = (wv > 0.f) ? sv : -1e30f;
        }
    }
    __syncthreads();

    // phase 2: masked softmax per row. 16 threads per row, interleaved scan.
    const int i = t >> 4, slot = t & 15;
    float m = -1e30f;
    #pragma unroll 8
    for (int jj = 0; jj < 64; ++jj) m = fmaxf(m, s_tile[i][slot + 16 * jj]);
    #pragma unroll
    for (int off = 1; off < 16; off <<= 1) m = fmaxf(m, __shfl_xor(m, off));
    const float* wrow = wm + (i0 + i) * NN;
    float sum = 0.f, aw = 0.f;
    #pragma unroll 4
    for (int jj = 0; jj < 64; ++jj) {
        const int j = slot + 16 * jj;
        const float sv = s_tile[i][j];
        const float p = (sv > -1e29f) ? __expf(sv - m) : 0.f;
        s_tile[i][j] = p;
        sum += p;
        aw = fmaf(p, fabsf(wrow[j]), aw);
    }
    #pragma unroll
    for (int off = 1; off < 16; off <<= 1) {
        sum += __shfl_xor(sum, off);
        aw  += __shfl_xor(aw, off);
    }
    const float inv = (m > -1e29f) ? 1.f / sum : 0.f;   // all-masked row -> output 0
    aw *= inv;
    __syncthreads();

    // phase 3: out[i][c] = inv * sum_j p[i][j] * v_t[h][c][j]; thread owns (i, c=slot).
    // p read: float4 LDS, same-address broadcast within i-group (conflict-free).
    // v read: per-lane float4 over j -> 16 distinct 16B segments per wave (256B/instr, L2-hot).
    const float* vt = v + h * (NN * CH) + slot * NN;
    float a0 = 0.f, a1 = 0.f, a2 = 0.f, a3 = 0.f, a4 = 0.f, a5 = 0.f, a6 = 0.f, a7 = 0.f;
    for (int j = 0; j < NN; j += 8) {
        const float4 p0 = *(const float4*)&s_tile[i][j];
        const float4 p1 = *(const float4*)&s_tile[i][j + 4];
        const float4 v0 = *(const float4*)&vt[j];
        const float4 v1 = *(const float4*)&vt[j + 4];
        a0 = fmaf(p0.x, v0.x, a0); a1 = fmaf(p0.y, v0.y, a1);
        a2 = fmaf(p0.z, v0.z, a2); a3 = fmaf(p0.w, v0.w, a3);
        a4 = fmaf(p1.x, v1.x, a4); a5 = fmaf(p1.y, v1.y, a5);
        a6 = fmaf(p1.z, v1.z, a6); a7 = fmaf(p1.w, v1.w, a7);
    }
    const float outv = (((a0 + a1) + (a2 + a3)) + ((a4 + a5) + (a6 + a7))) * inv + aw * we_l[slot];
    const int idx = (i0 + i) * HD + h * CH + slot;
    x[idx] = x[idx] + outv + skip[idx];   // residual + skip; slice owned exclusively by this block
}

// ---------------- launch ----------------
extern "C" void kernel_launch(void* const* d_in, const int* in_sizes, int n_in,
                              void* d_out, int out_size, void* d_ws, size_t ws_size,
                              hipStream_t stream) {
    const float* ent = (const float*)d_in[2];
    const float* W1  = (const float*)d_in[3];
    const float* b1  = (const float*)d_in[4];
    const float* W2  = (const float*)d_in[5];
    const float* b2  = (const float*)d_in[6];
    const float* Wq  = (const float*)d_in[7];
    const float* bq  = (const float*)d_in[8];
    const float* Wk  = (const float*)d_in[9];
    const float* bk  = (const float*)d_in[10];
    const float* Wv  = (const float*)d_in[11];
    const float* bv  = (const float*)d_in[12];
    const float* We  = (const float*)d_in[13];
    const float* Ws  = (const float*)d_in[14];
    const float* bs  = (const float*)d_in[15];

    float* ws = (float*)d_ws;
    float* wm = ws;                        // [1024][1024]  signed w (mask in sign)
    float* q  = ws + NN * NN;              // [8][1024][16]  (reused as 'a' before layers)
    float* k  = q  + NN * HD;              //                (reused as 'b')
    float* v  = k  + NN * HD;              // [8][16][1024]  transposed
    float* sk = v  + NN * HD;
    float* x  = (float*)d_out;             // running entity state

    // x <- entity_embeddings
    hipMemcpyAsync(x, ent, NN * HD * sizeof(float), hipMemcpyDeviceToDevice, stream);

    // edge graph (built once from initial embeddings)
    k_edge_ab<<<NN, 256, 0, stream>>>(ent, W1, b1, q /*a*/, k /*b*/);
    k_edge_w<<<dim3(32, 64), 256, 0, stream>>>(q, k, W2, b2, wm);

    for (int l = 0; l < NLAYERS; ++l) {
        k_proj<<<NN, 256, 0, stream>>>(x,
            Wq + l * HD * HD, bq + l * HD, Wk + l * HD * HD, bk + l * HD,
            Wv + l * HD * HD, bv + l * HD, Ws + l * HD * HD, bs + l * HD,
            q, k, v, sk);
        k_attn<<<dim3(NH, 64), 256, 0, stream>>>(q, k, v, sk, wm, We + l * HD, x);
    }
}

// Round 3
// 363.757 us; speedup vs baseline: 1.0651x; 1.0651x over previous
//
#include <hip/hip_runtime.h>
#include <math.h>

#define NN 1024     // entities
#define HD 128      // hidden dim
#define NH 8        // heads
#define CH 16       // dim per head
#define NLAYERS 3

#define TT 8        // targets per attention block
#define SF 1040     // s_tile f32 row stride: 1040*4=4160B; 4160 mod 128 = 64 -> i-row shifts 16 banks (2-way, free)

// ---------------- K1: a = x@W1[:128], b = x@W1[128:] + b1 ----------------
__global__ __launch_bounds__(256) void k_edge_ab(
        const float* __restrict__ x, const float* __restrict__ W1,
        const float* __restrict__ b1, float* __restrict__ a, float* __restrict__ b) {
    __shared__ float xr[HD];
    const int row = blockIdx.x, t = threadIdx.x;
    if (t < HD) xr[t] = x[row * HD + t];
    __syncthreads();
    const int c = t & 127;
    const int half = t >> 7;                 // 0 -> a, 1 -> b
    const float* w = W1 + half * HD * HD + c;
    float acc = half ? b1[c] : 0.f;          // fold b1 into b
    #pragma unroll 8
    for (int kk = 0; kk < HD; ++kk) acc = fmaf(xr[kk], w[kk * HD], acc);
    (half ? b : a)[row * HD + c] = acc;
}

// ---------------- K2: wm[t][s] = sign(mask) * sigmoid(logit[s][t]) ----------------
__global__ __launch_bounds__(256) void k_edge_w(
        const float* __restrict__ a, const float* __restrict__ bb,
        const float* __restrict__ W2, const float* __restrict__ b2,
        float* __restrict__ wm) {
    __shared__ float al[32][HD + 1];
    __shared__ float bl[16][HD];
    __shared__ float w2[HD];
    const int t = threadIdx.x;
    const int s0 = blockIdx.x * 32, t0 = blockIdx.y * 16;
    for (int i = t; i < 32 * HD; i += 256) al[i >> 7][i & 127] = a[(s0 + (i >> 7)) * HD + (i & 127)];
    for (int i = t; i < 16 * HD; i += 256) bl[i >> 7][i & 127] = bb[(t0 + (i >> 7)) * HD + (i & 127)];
    if (t < HD) w2[t] = W2[t];
    __syncthreads();
    const int s = t & 31, tt = t >> 5;
    float acc0 = 0.f, acc1 = 0.f;
    #pragma unroll 4
    for (int h = 0; h < HD; ++h) {
        const float av = al[s][h], wv = w2[h];
        acc0 = fmaf(fmaxf(av + bl[tt][h],     0.f), wv, acc0);
        acc1 = fmaf(fmaxf(av + bl[tt + 8][h], 0.f), wv, acc1);
    }
    const float bias = b2[0];
    const float l0 = acc0 + bias, l1 = acc1 + bias;
    const float w0 = 1.f / (1.f + __expf(-l0));
    const float w1 = 1.f / (1.f + __expf(-l1));
    wm[(t0 + tt    ) * NN + s0 + s] = (l0 > 0.f) ? w0 : -w0;   // sign encodes mask
    wm[(t0 + tt + 8) * NN + s0 + s] = (l1 > 0.f) ? w1 : -w1;
}

// ---------------- K3: per-layer projections q,k,v ([h][n][c]) + skip ----------------
__global__ __launch_bounds__(256) void k_proj(
        const float* __restrict__ x,
        const float* __restrict__ Wq, const float* __restrict__ bq,
        const float* __restrict__ Wk, const float* __restrict__ bk,
        const float* __restrict__ Wv, const float* __restrict__ bv,
        const float* __restrict__ Wsk, const float* __restrict__ bsk,
        float* __restrict__ q, float* __restrict__ k,
        float* __restrict__ v, float* __restrict__ skip) {
    __shared__ float xr[HD];
    const int row = blockIdx.x, t = threadIdx.x;
    if (t < HD) xr[t] = x[row * HD + t];
    __syncthreads();
    const int c = t & 127;
    const bool lo = t < 128;
    const float* WA = lo ? Wq : Wv;
    const float* WB = lo ? Wk : Wsk;
    float a0 = lo ? bq[c] : bv[c];
    float a1 = lo ? bk[c] : bsk[c];
    #pragma unroll 8
    for (int kk = 0; kk < HD; ++kk) {
        const float xv = xr[kk];
        a0 = fmaf(xv, WA[kk * HD + c], a0);
        a1 = fmaf(xv, WB[kk * HD + c], a1);
    }
    const int hnc = (c >> 4) * (NN * CH) + row * CH + (c & 15);
    if (lo) { q[hnc] = a0; k[hnc] = a1; }
    else    { v[hnc] = a0; skip[row * HD + c] = a1; }
}

// ---------------- K4: fused attention, one (head, 8-target tile); x updated in place ----------------
__global__ __launch_bounds__(256, 4) void k_attn(
        const float* __restrict__ q, const float* __restrict__ k,
        const float* __restrict__ v, const float* __restrict__ skip,
        const float* __restrict__ wm, const float* __restrict__ We,
        float* __restrict__ x) {
    __shared__ float s_tile[TT][SF];   // 33.3 KB -> with grid 1024 blocks: 4 blocks/CU
    __shared__ float q_l[TT][CH];      // q * 0.25 (scale folded)
    __shared__ float we_l[CH];
    __shared__ float qwe_l[TT];
    __shared__ float inv_l[TT], aw_l[TT];
    const int h  = blockIdx.x;
    const int i0 = blockIdx.y * TT;
    const int t  = threadIdx.x;

    if (t < TT * CH) q_l[t >> 4][t & 15] = q[h * (NN * CH) + (i0 + (t >> 4)) * CH + (t & 15)] * 0.25f;
    if (t >= 128 && t < 128 + CH) we_l[t - 128] = We[h * CH + (t - 128)];
    __syncthreads();
    if (t < TT) {
        float sv = 0.f;
        #pragma unroll
        for (int c = 0; c < CH; ++c) sv = fmaf(q_l[t][c], we_l[c], sv);
        qwe_l[t] = sv;                 // carries the 0.25 scale
    }
    __syncthreads();

    // ---- phase 1: logits. Each thread: 2 k-rows per pass (q LDS reads amortized), 2 passes. ----
    const float* kh = k + h * (NN * CH);
    #pragma unroll
    for (int p = 0; p < 2; ++p) {
        const int j0 = t + 512 * p, j1 = j0 + 256;
        float kr0[CH], kr1[CH];
        {
            const float4* k0 = (const float4*)(kh + j0 * CH);
            const float4* k1 = (const float4*)(kh + j1 * CH);
            #pragma unroll
            for (int qq = 0; qq < 4; ++qq) {
                const float4 r0 = k0[qq], r1 = k1[qq];
                kr0[qq*4+0]=r0.x; kr0[qq*4+1]=r0.y; kr0[qq*4+2]=r0.z; kr0[qq*4+3]=r0.w;
                kr1[qq*4+0]=r1.x; kr1[qq*4+1]=r1.y; kr1[qq*4+2]=r1.z; kr1[qq*4+3]=r1.w;
            }
        }
        #pragma unroll
        for (int i = 0; i < TT; ++i) {
            float d0 = 0.f, d1 = 0.f;
            #pragma unroll
            for (int c = 0; c < CH; ++c) {
                const float qc = q_l[i][c];      // broadcast ds_read (merged to b128 by compiler)
                d0 = fmaf(qc, kr0[c], d0);
                d1 = fmaf(qc, kr1[c], d1);
            }
            const float wv0 = wm[(i0 + i) * NN + j0];
            const float wv1 = wm[(i0 + i) * NN + j1];
            const float qe = qwe_l[i];
            const float s0 = d0 + qe * fabsf(wv0);
            const float s1 = d1 + qe * fabsf(wv1);
            s_tile[i][j0] = (wv0 > 0.f) ? s0 : -1e30f;
            s_tile[i][j1] = (wv1 > 0.f) ? s1 : -1e30f;
        }
    }
    __syncthreads();

    // ---- phase 2: masked softmax per row; 32 threads/row, interleaved (bank 1-way). ----
    const int i2 = t >> 5, slot = t & 31;
    float m = -1e30f;
    #pragma unroll 8
    for (int jj = 0; jj < 32; ++jj) m = fmaxf(m, s_tile[i2][slot + 32 * jj]);
    #pragma unroll
    for (int off = 1; off < 32; off <<= 1) m = fmaxf(m, __shfl_xor(m, off));
    const float* wrow = wm + (i0 + i2) * NN;
    float sum = 0.f, aw = 0.f;
    #pragma unroll 4
    for (int jj = 0; jj < 32; ++jj) {
        const int j = slot + 32 * jj;
        const float sv = s_tile[i2][j];
        const float pv = (sv > -1e29f) ? __expf(sv - m) : 0.f;
        s_tile[i2][j] = pv;
        sum += pv;
        aw = fmaf(pv, fabsf(wrow[j]), aw);
    }
    #pragma unroll
    for (int off = 1; off < 32; off <<= 1) {
        sum += __shfl_xor(sum, off);
        aw  += __shfl_xor(aw, off);
    }
    if (slot == 0) {
        const float inv = (m > -1e29f) ? 1.f / sum : 0.f;   // all-masked row -> 0
        inv_l[i2] = inv;
        aw_l[i2]  = aw * inv;
    }
    __syncthreads();

    // ---- phase 3: out[i][c] = inv * sum_j p[i][j] v[j][c]. thread = (i, jb, c4). ----
    const int i3 = t >> 5, jb = (t >> 2) & 7, c4 = t & 3;
    const float* vh = v + h * (NN * CH) + c4 * 4;
    float a0 = 0.f, a1 = 0.f, a2 = 0.f, a3 = 0.f;
    #pragma unroll 4
    for (int gg = 0; gg < 32; ++gg) {
        const int j0 = jb * 4 + 32 * gg;
        const float4 pp = *(const float4*)&s_tile[i3][j0];            // 128B contig across jb lanes
        const float4 v0 = *(const float4*)&vh[(j0 + 0) * CH];
        const float4 v1 = *(const float4*)&vh[(j0 + 1) * CH];
        const float4 v2 = *(const float4*)&vh[(j0 + 2) * CH];
        const float4 v3 = *(const float4*)&vh[(j0 + 3) * CH];
        a0 = fmaf(pp.x, v0.x, a0); a1 = fmaf(pp.x, v0.y, a1); a2 = fmaf(pp.x, v0.z, a2); a3 = fmaf(pp.x, v0.w, a3);
        a0 = fmaf(pp.y, v1.x, a0); a1 = fmaf(pp.y, v1.y, a1); a2 = fmaf(pp.y, v1.z, a2); a3 = fmaf(pp.y, v1.w, a3);
        a0 = fmaf(pp.z, v2.x, a0); a1 = fmaf(pp.z, v2.y, a1); a2 = fmaf(pp.z, v2.z, a2); a3 = fmaf(pp.z, v2.w, a3);
        a0 = fmaf(pp.w, v3.x, a0); a1 = fmaf(pp.w, v3.y, a1); a2 = fmaf(pp.w, v3.z, a2); a3 = fmaf(pp.w, v3.w, a3);
    }
    a0 += __shfl_xor(a0, 4); a0 += __shfl_xor(a0, 8); a0 += __shfl_xor(a0, 16);
    a1 += __shfl_xor(a1, 4); a1 += __shfl_xor(a1, 8); a1 += __shfl_xor(a1, 16);
    a2 += __shfl_xor(a2, 4); a2 += __shfl_xor(a2, 8); a2 += __shfl_xor(a2, 16);
    a3 += __shfl_xor(a3, 4); a3 += __shfl_xor(a3, 8); a3 += __shfl_xor(a3, 16);
    if (jb == 0) {
        const float inv = inv_l[i3], awv = aw_l[i3];
        const int idx = (i0 + i3) * HD + h * CH + c4 * 4;
        const float4 xo = *(const float4*)&x[idx];
        const float4 so = *(const float4*)&skip[idx];
        float4 o;
        o.x = xo.x + so.x + a0 * inv + awv * we_l[c4 * 4 + 0];
        o.y = xo.y + so.y + a1 * inv + awv * we_l[c4 * 4 + 1];
        o.z = xo.z + so.z + a2 * inv + awv * we_l[c4 * 4 + 2];
        o.w = xo.w + so.w + a3 * inv + awv * we_l[c4 * 4 + 3];
        *(float4*)&x[idx] = o;       // slice owned exclusively by this block
    }
}

// ---------------- launch ----------------
extern "C" void kernel_launch(void* const* d_in, const int* in_sizes, int n_in,
                              void* d_out, int out_size, void* d_ws, size_t ws_size,
                              hipStream_t stream) {
    const float* ent = (const float*)d_in[2];
    const float* W1  = (const float*)d_in[3];
    const float* b1  = (const float*)d_in[4];
    const float* W2  = (const float*)d_in[5];
    const float* b2  = (const float*)d_in[6];
    const float* Wq  = (const float*)d_in[7];
    const float* bq  = (const float*)d_in[8];
    const float* Wk  = (const float*)d_in[9];
    const float* bk  = (const float*)d_in[10];
    const float* Wv  = (const float*)d_in[11];
    const float* bv  = (const float*)d_in[12];
    const float* We  = (const float*)d_in[13];
    const float* Ws  = (const float*)d_in[14];
    const float* bs  = (const float*)d_in[15];

    float* ws = (float*)d_ws;
    float* wm = ws;                        // [1024][1024]  signed w (mask in sign)
    float* q  = ws + NN * NN;              // [8][1024][16]  (reused as 'a' before layers)
    float* k  = q  + NN * HD;              //                (reused as 'b')
    float* v  = k  + NN * HD;              // [8][1024][16]
    float* sk = v  + NN * HD;
    float* x  = (float*)d_out;             // running entity state

    hipMemcpyAsync(x, ent, NN * HD * sizeof(float), hipMemcpyDeviceToDevice, stream);

    k_edge_ab<<<NN, 256, 0, stream>>>(ent, W1, b1, q /*a*/, k /*b*/);
    k_edge_w<<<dim3(32, 64), 256, 0, stream>>>(q, k, W2, b2, wm);

    for (int l = 0; l < NLAYERS; ++l) {
        k_proj<<<NN, 256, 0, stream>>>(x,
            Wq + l * HD * HD, bq + l * HD, Wk + l * HD * HD, bk + l * HD,
            Wv + l * HD * HD, bv + l * HD, Ws + l * HD * HD, bs + l * HD,
            q, k, v, sk);
        k_attn<<<dim3(NH, NN / TT), 256, 0, stream>>>(q, k, v, sk, wm, We + l * HD, x);
    }
}

// Round 4
// 258.686 us; speedup vs baseline: 1.4977x; 1.4062x over previous
//
#include <hip/hip_runtime.h>
#include <math.h>

#define NN 1024     // entities
#define HD 128      // hidden dim
#define NH 8        // heads
#define CH 16       // dim per head
#define NLAYERS 3

#define TT 8        // targets per attention block
#define SF 1040     // s_tile f32 row stride: 1040*4=4160B; 4160 mod 128 = 64 -> i-row shifts 16 banks (2-way, free)

// ---------------- K1: a = x@W1[:128], b = x@W1[128:] + b1 ----------------
__global__ __launch_bounds__(256) void k_edge_ab(
        const float* __restrict__ x, const float* __restrict__ W1,
        const float* __restrict__ b1, float* __restrict__ a, float* __restrict__ b) {
    __shared__ float xr[HD];
    const int row = blockIdx.x, t = threadIdx.x;
    if (t < HD) xr[t] = x[row * HD + t];
    __syncthreads();
    const int c = t & 127;
    const int half = t >> 7;                 // 0 -> a, 1 -> b
    const float* w = W1 + half * HD * HD + c;
    float acc = half ? b1[c] : 0.f;          // fold b1 into b
    #pragma unroll 8
    for (int kk = 0; kk < HD; ++kk) acc = fmaf(xr[kk], w[kk * HD], acc);
    (half ? b : a)[row * HD + c] = acc;
}

// ---------------- K2: wm[t][s] = sign(mask) * sigmoid(logit[s][t]) ----------------
__global__ __launch_bounds__(256) void k_edge_w(
        const float* __restrict__ a, const float* __restrict__ bb,
        const float* __restrict__ W2, const float* __restrict__ b2,
        float* __restrict__ wm) {
    __shared__ float al[32][HD + 1];
    __shared__ float bl[16][HD];
    __shared__ float w2[HD];
    const int t = threadIdx.x;
    const int s0 = blockIdx.x * 32, t0 = blockIdx.y * 16;
    for (int i = t; i < 32 * HD; i += 256) al[i >> 7][i & 127] = a[(s0 + (i >> 7)) * HD + (i & 127)];
    for (int i = t; i < 16 * HD; i += 256) bl[i >> 7][i & 127] = bb[(t0 + (i >> 7)) * HD + (i & 127)];
    if (t < HD) w2[t] = W2[t];
    __syncthreads();
    const int s = t & 31, tt = t >> 5;
    float acc0 = 0.f, acc1 = 0.f;
    #pragma unroll 4
    for (int h = 0; h < HD; ++h) {
        const float av = al[s][h], wv = w2[h];
        acc0 = fmaf(fmaxf(av + bl[tt][h],     0.f), wv, acc0);
        acc1 = fmaf(fmaxf(av + bl[tt + 8][h], 0.f), wv, acc1);
    }
    const float bias = b2[0];
    const float l0 = acc0 + bias, l1 = acc1 + bias;
    const float w0 = 1.f / (1.f + __expf(-l0));
    const float w1 = 1.f / (1.f + __expf(-l1));
    wm[(t0 + tt    ) * NN + s0 + s] = (l0 > 0.f) ? w0 : -w0;   // sign encodes mask
    wm[(t0 + tt + 8) * NN + s0 + s] = (l1 > 0.f) ? w1 : -w1;
}

// ---------------- K3: per-layer projections q,k,v ([h][n][c]) + skip ----------------
__global__ __launch_bounds__(256) void k_proj(
        const float* __restrict__ x,
        const float* __restrict__ Wq, const float* __restrict__ bq,
        const float* __restrict__ Wk, const float* __restrict__ bk,
        const float* __restrict__ Wv, const float* __restrict__ bv,
        const float* __restrict__ Wsk, const float* __restrict__ bsk,
        float* __restrict__ q, float* __restrict__ k,
        float* __restrict__ v, float* __restrict__ skip) {
    __shared__ float xr[HD];
    const int row = blockIdx.x, t = threadIdx.x;
    if (t < HD) xr[t] = x[row * HD + t];
    __syncthreads();
    const int c = t & 127;
    const bool lo = t < 128;
    const float* WA = lo ? Wq : Wv;
    const float* WB = lo ? Wk : Wsk;
    float a0 = lo ? bq[c] : bv[c];
    float a1 = lo ? bk[c] : bsk[c];
    #pragma unroll 8
    for (int kk = 0; kk < HD; ++kk) {
        const float xv = xr[kk];
        a0 = fmaf(xv, WA[kk * HD + c], a0);
        a1 = fmaf(xv, WB[kk * HD + c], a1);
    }
    const int hnc = (c >> 4) * (NN * CH) + row * CH + (c & 15);
    if (lo) { q[hnc] = a0; k[hnc] = a1; }
    else    { v[hnc] = a0; skip[row * HD + c] = a1; }
}

// ---------------- K4: fused attention, one (head, 8-target tile); x updated in place ----------------
__global__ __launch_bounds__(256) void k_attn(
        const float* __restrict__ q, const float* __restrict__ k,
        const float* __restrict__ v, const float* __restrict__ skip,
        const float* __restrict__ wm, const float* __restrict__ We,
        float* __restrict__ x) {
    __shared__ float s_tile[TT][SF];   // 33.3 KB -> up to 4 blocks/CU by LDS
    __shared__ float q_l[TT][CH];      // q * 0.25 (scale folded)
    __shared__ float we_l[CH];
    __shared__ float qwe_l[TT];
    __shared__ float inv_l[TT], aw_l[TT];
    const int h  = blockIdx.x;
    const int i0 = blockIdx.y * TT;
    const int t  = threadIdx.x;

    if (t < TT * CH) q_l[t >> 4][t & 15] = q[h * (NN * CH) + (i0 + (t >> 4)) * CH + (t & 15)] * 0.25f;
    if (t >= 128 && t < 128 + CH) we_l[t - 128] = We[h * CH + (t - 128)];
    __syncthreads();
    if (t < TT) {
        float sv = 0.f;
        #pragma unroll
        for (int c = 0; c < CH; ++c) sv = fmaf(q_l[t][c], we_l[c], sv);
        qwe_l[t] = sv;                 // carries the 0.25 scale
    }
    __syncthreads();

    // ---- phase 1: logits. One k-row (16 f32) per thread per pass; 4 passes. ----
    const float* kh = k + h * (NN * CH);
    #pragma unroll
    for (int p = 0; p < 4; ++p) {
        const int j = t + 256 * p;
        const float4* kp = (const float4*)(kh + j * CH);
        const float4 r0 = kp[0], r1 = kp[1], r2 = kp[2], r3 = kp[3];
        const float kr[CH] = {r0.x, r0.y, r0.z, r0.w, r1.x, r1.y, r1.z, r1.w,
                              r2.x, r2.y, r2.z, r2.w, r3.x, r3.y, r3.z, r3.w};
        #pragma unroll
        for (int i = 0; i < TT; ++i) {
            float dot = 0.f;
            #pragma unroll
            for (int c = 0; c < CH; ++c) dot = fmaf(q_l[i][c], kr[c], dot);
            const float wv = wm[(i0 + i) * NN + j];          // sign = mask
            const float sv = dot + qwe_l[i] * fabsf(wv);
            s_tile[i][j] = (wv > 0.f) ? sv : -1e30f;
        }
    }
    __syncthreads();

    // ---- phase 2: masked softmax per row; 32 threads/row, interleaved (bank 1-way). ----
    const int i2 = t >> 5, slot = t & 31;
    float m = -1e30f;
    #pragma unroll 8
    for (int jj = 0; jj < 32; ++jj) m = fmaxf(m, s_tile[i2][slot + 32 * jj]);
    #pragma unroll
    for (int off = 1; off < 32; off <<= 1) m = fmaxf(m, __shfl_xor(m, off));
    const float* wrow = wm + (i0 + i2) * NN;
    float sum = 0.f, aw = 0.f;
    #pragma unroll 4
    for (int jj = 0; jj < 32; ++jj) {
        const int j = slot + 32 * jj;
        const float sv = s_tile[i2][j];
        const float pv = (sv > -1e29f) ? __expf(sv - m) : 0.f;
        s_tile[i2][j] = pv;
        sum += pv;
        aw = fmaf(pv, fabsf(wrow[j]), aw);
    }
    #pragma unroll
    for (int off = 1; off < 32; off <<= 1) {
        sum += __shfl_xor(sum, off);
        aw  += __shfl_xor(aw, off);
    }
    if (slot == 0) {
        const float inv = (m > -1e29f) ? 1.f / sum : 0.f;   // all-masked row -> 0
        inv_l[i2] = inv;
        aw_l[i2]  = aw * inv;
    }
    __syncthreads();

    // ---- phase 3: out[i][c] = inv * sum_j p[i][j] v[j][c]. thread = (i, jb, c4). ----
    const int i3 = t >> 5, jb = (t >> 2) & 7, c4 = t & 3;
    const float* vh = v + h * (NN * CH) + c4 * 4;
    float a0 = 0.f, a1 = 0.f, a2 = 0.f, a3 = 0.f;
    #pragma unroll 4
    for (int gg = 0; gg < 32; ++gg) {
        const int j0 = jb * 4 + 32 * gg;
        const float4 pp = *(const float4*)&s_tile[i3][j0];            // 128B contig across jb lanes
        const float4 v0 = *(const float4*)&vh[(j0 + 0) * CH];
        const float4 v1 = *(const float4*)&vh[(j0 + 1) * CH];
        const float4 v2 = *(const float4*)&vh[(j0 + 2) * CH];
        const float4 v3 = *(const float4*)&vh[(j0 + 3) * CH];
        a0 = fmaf(pp.x, v0.x, a0); a1 = fmaf(pp.x, v0.y, a1); a2 = fmaf(pp.x, v0.z, a2); a3 = fmaf(pp.x, v0.w, a3);
        a0 = fmaf(pp.y, v1.x, a0); a1 = fmaf(pp.y, v1.y, a1); a2 = fmaf(pp.y, v1.z, a2); a3 = fmaf(pp.y, v1.w, a3);
        a0 = fmaf(pp.z, v2.x, a0); a1 = fmaf(pp.z, v2.y, a1); a2 = fmaf(pp.z, v2.z, a2); a3 = fmaf(pp.z, v2.w, a3);
        a0 = fmaf(pp.w, v3.x, a0); a1 = fmaf(pp.w, v3.y, a1); a2 = fmaf(pp.w, v3.z, a2); a3 = fmaf(pp.w, v3.w, a3);
    }
    a0 += __shfl_xor(a0, 4); a0 += __shfl_xor(a0, 8); a0 += __shfl_xor(a0, 16);
    a1 += __shfl_xor(a1, 4); a1 += __shfl_xor(a1, 8); a1 += __shfl_xor(a1, 16);
    a2 += __shfl_xor(a2, 4); a2 += __shfl_xor(a2, 8); a2 += __shfl_xor(a2, 16);
    a3 += __shfl_xor(a3, 4); a3 += __shfl_xor(a3, 8); a3 += __shfl_xor(a3, 16);
    if (jb == 0) {
        const float inv = inv_l[i3], awv = aw_l[i3];
        const int idx = (i0 + i3) * HD + h * CH + c4 * 4;
        const float4 xo = *(const float4*)&x[idx];
        const float4 so = *(const float4*)&skip[idx];
        float4 o;
        o.x = xo.x + so.x + a0 * inv + awv * we_l[c4 * 4 + 0];
        o.y = xo.y + so.y + a1 * inv + awv * we_l[c4 * 4 + 1];
        o.z = xo.z + so.z + a2 * inv + awv * we_l[c4 * 4 + 2];
        o.w = xo.w + so.w + a3 * inv + awv * we_l[c4 * 4 + 3];
        *(float4*)&x[idx] = o;       // slice owned exclusively by this block
    }
}

// ---------------- launch ----------------
extern "C" void kernel_launch(void* const* d_in, const int* in_sizes, int n_in,
                              void* d_out, int out_size, void* d_ws, size_t ws_size,
                              hipStream_t stream) {
    const float* ent = (const float*)d_in[2];
    const float* W1  = (const float*)d_in[3];
    const float* b1  = (const float*)d_in[4];
    const float* W2  = (const float*)d_in[5];
    const float* b2  = (const float*)d_in[6];
    const float* Wq  = (const float*)d_in[7];
    const float* bq  = (const float*)d_in[8];
    const float* Wk  = (const float*)d_in[9];
    const float* bk  = (const float*)d_in[10];
    const float* Wv  = (const float*)d_in[11];
    const float* bv  = (const float*)d_in[12];
    const float* We  = (const float*)d_in[13];
    const float* Ws  = (const float*)d_in[14];
    const float* bs  = (const float*)d_in[15];

    float* ws = (float*)d_ws;
    float* wm = ws;                        // [1024][1024]  signed w (mask in sign)
    float* q  = ws + NN * NN;              // [8][1024][16]  (reused as 'a' before layers)
    float* k  = q  + NN * HD;              //                (reused as 'b')
    float* v  = k  + NN * HD;              // [8][1024][16]
    float* sk = v  + NN * HD;
    float* x  = (float*)d_out;             // running entity state

    hipMemcpyAsync(x, ent, NN * HD * sizeof(float), hipMemcpyDeviceToDevice, stream);

    k_edge_ab<<<NN, 256, 0, stream>>>(ent, W1, b1, q /*a*/, k /*b*/);
    k_edge_w<<<dim3(32, 64), 256, 0, stream>>>(q, k, W2, b2, wm);

    for (int l = 0; l < NLAYERS; ++l) {
        k_proj<<<NN, 256, 0, stream>>>(x,
            Wq + l * HD * HD, bq + l * HD, Wk + l * HD * HD, bk + l * HD,
            Wv + l * HD * HD, bv + l * HD, Ws + l * HD * HD, bs + l * HD,
            q, k, v, sk);
        k_attn<<<dim3(NH, NN / TT), 256, 0, stream>>>(q, k, v, sk, wm, We + l * HD, x);
    }
}

// Round 5
// 154.121 us; speedup vs baseline: 2.5139x; 1.6785x over previous
//
#include <hip/hip_runtime.h>
#include <math.h>

#define NN 1024     // entities
#define HD 128      // hidden dim
#define NH 8        // heads
#define CH 16       // dim per head
#define NLAYERS 3

#define TT 8        // targets per attention block
#define SF 1040     // s_tile f32 row stride: 4160B; 4160 mod 128 = 64 -> adjacent rows shift 16 banks (2-way, free)

__device__ __forceinline__ float bf16_to_f32(unsigned short u) {
    union { unsigned int i; float f; } x; x.i = ((unsigned int)u) << 16; return x.f;
}
__device__ __forceinline__ unsigned short f32_to_bf16(float f) {
    union { float f; unsigned int i; } x; x.f = f;
    const unsigned int r = x.i + 0x7FFFu + ((x.i >> 16) & 1u);   // RNE
    return (unsigned short)(r >> 16);
}

// ---------------- K1: a = x@W1[:128], b = x@W1[128:] + b1 ----------------
__global__ __launch_bounds__(256) void k_edge_ab(
        const float* __restrict__ x, const float* __restrict__ W1,
        const float* __restrict__ b1, float* __restrict__ a, float* __restrict__ b) {
    __shared__ float xr[HD];
    const int row = blockIdx.x, t = threadIdx.x;
    if (t < HD) xr[t] = x[row * HD + t];
    __syncthreads();
    const int c = t & 127;
    const int half = t >> 7;                 // 0 -> a, 1 -> b
    const float* w = W1 + half * HD * HD + c;
    float acc = half ? b1[c] : 0.f;          // fold b1 into b
    #pragma unroll 8
    for (int kk = 0; kk < HD; ++kk) acc = fmaf(xr[kk], w[kk * HD], acc);
    (half ? b : a)[row * HD + c] = acc;
}

// ---------------- K2: wm[t][s] = bf16( sign(mask) * sigmoid(logit[s][t]) ) ----------------
__global__ __launch_bounds__(256) void k_edge_w(
        const float* __restrict__ a, const float* __restrict__ bb,
        const float* __restrict__ W2, const float* __restrict__ b2,
        unsigned short* __restrict__ wm) {
    __shared__ float al[32][HD + 1];
    __shared__ float bl[16][HD];
    __shared__ float w2[HD];
    const int t = threadIdx.x;
    const int s0 = blockIdx.x * 32, t0 = blockIdx.y * 16;
    for (int i = t; i < 32 * HD; i += 256) al[i >> 7][i & 127] = a[(s0 + (i >> 7)) * HD + (i & 127)];
    for (int i = t; i < 16 * HD; i += 256) bl[i >> 7][i & 127] = bb[(t0 + (i >> 7)) * HD + (i & 127)];
    if (t < HD) w2[t] = W2[t];
    __syncthreads();
    const int s = t & 31, tt = t >> 5;
    float acc0 = 0.f, acc1 = 0.f;
    #pragma unroll 4
    for (int h = 0; h < HD; ++h) {
        const float av = al[s][h], wv = w2[h];
        acc0 = fmaf(fmaxf(av + bl[tt][h],     0.f), wv, acc0);
        acc1 = fmaf(fmaxf(av + bl[tt + 8][h], 0.f), wv, acc1);
    }
    const float bias = b2[0];
    const float l0 = acc0 + bias, l1 = acc1 + bias;
    const float w0 = 1.f / (1.f + __expf(-l0));
    const float w1 = 1.f / (1.f + __expf(-l1));
    wm[(t0 + tt    ) * NN + s0 + s] = f32_to_bf16((l0 > 0.f) ? w0 : -w0);   // sign encodes mask
    wm[(t0 + tt + 8) * NN + s0 + s] = f32_to_bf16((l1 > 0.f) ? w1 : -w1);
}

// ---------------- K3: per-layer projections q,k,v ([h][n][c]) + skip ----------------
__global__ __launch_bounds__(256) void k_proj(
        const float* __restrict__ x,
        const float* __restrict__ Wq, const float* __restrict__ bq,
        const float* __restrict__ Wk, const float* __restrict__ bk,
        const float* __restrict__ Wv, const float* __restrict__ bv,
        const float* __restrict__ Wsk, const float* __restrict__ bsk,
        float* __restrict__ q, float* __restrict__ k,
        float* __restrict__ v, float* __restrict__ skip) {
    __shared__ float xr[HD];
    const int row = blockIdx.x, t = threadIdx.x;
    if (t < HD) xr[t] = x[row * HD + t];
    __syncthreads();
    const int c = t & 127;
    const bool lo = t < 128;
    const float* WA = lo ? Wq : Wv;
    const float* WB = lo ? Wk : Wsk;
    float a0 = lo ? bq[c] : bv[c];
    float a1 = lo ? bk[c] : bsk[c];
    #pragma unroll 8
    for (int kk = 0; kk < HD; ++kk) {
        const float xv = xr[kk];
        a0 = fmaf(xv, WA[kk * HD + c], a0);
        a1 = fmaf(xv, WB[kk * HD + c], a1);
    }
    const int hnc = (c >> 4) * (NN * CH) + row * CH + (c & 15);
    if (lo) { q[hnc] = a0; k[hnc] = a1; }
    else    { v[hnc] = a0; skip[row * HD + c] = a1; }
}

// ---------------- K4: fused attention, one (head, 8-target tile); x updated in place ----------------
__global__ __launch_bounds__(256) void k_attn(
        const float* __restrict__ q, const float* __restrict__ k,
        const float* __restrict__ v, const float* __restrict__ skip,
        const unsigned short* __restrict__ wm, const float* __restrict__ We,
        float* __restrict__ x) {
    __shared__ float s_tile[TT][SF];   // 33.3 KB
    __shared__ float q_l[TT][CH];      // q * 0.25 (scale folded)
    __shared__ float we_l[CH];
    __shared__ float qwe_l[TT];
    __shared__ float inv_l[TT], aw_l[TT];
    const int h  = blockIdx.x;
    const int i0 = blockIdx.y * TT;
    const int t  = threadIdx.x;

    if (t < TT * CH) q_l[t >> 4][t & 15] = q[h * (NN * CH) + (i0 + (t >> 4)) * CH + (t & 15)] * 0.25f;
    if (t >= 128 && t < 128 + CH) we_l[t - 128] = We[h * CH + (t - 128)];
    __syncthreads();
    if (t < TT) {
        float sv = 0.f;
        #pragma unroll
        for (int c = 0; c < CH; ++c) sv = fmaf(q_l[t][c], we_l[c], sv);
        qwe_l[t] = sv;                 // carries the 0.25 scale
    }
    __syncthreads();

    // ---- phase 1: logits. 2 groups x 128 threads; group g owns targets g*4..g*4+3. ----
    // qr[4][16] = 64 VGPR deliberate; pass loop NOT unrolled (keeps kr[16] single copy).
    const int g  = t >> 7;             // 0/1
    const int lj = t & 127;            // lane within group
    float qr[4][CH], qe[4];
    #pragma unroll
    for (int i = 0; i < 4; ++i) {
        qe[i] = qwe_l[g * 4 + i];
        #pragma unroll
        for (int c = 0; c < CH; ++c) qr[i][c] = q_l[g * 4 + i][c];
    }
    const float* kh = k + h * (NN * CH);
    #pragma unroll 1
    for (int p = 0; p < 8; ++p) {
        const int j = lj + 128 * p;
        const float4* kp = (const float4*)(kh + j * CH);
        const float4 r0 = kp[0], r1 = kp[1], r2 = kp[2], r3 = kp[3];
        const float kr[CH] = {r0.x, r0.y, r0.z, r0.w, r1.x, r1.y, r1.z, r1.w,
                              r2.x, r2.y, r2.z, r2.w, r3.x, r3.y, r3.z, r3.w};
        #pragma unroll
        for (int i = 0; i < 4; ++i) {
            float dot = 0.f;
            #pragma unroll
            for (int c = 0; c < CH; ++c) dot = fmaf(qr[i][c], kr[c], dot);
            const float wv = bf16_to_f32(wm[(i0 + g * 4 + i) * NN + j]);   // sign = mask
            const float sv = dot + qe[i] * fabsf(wv);
            s_tile[g * 4 + i][j] = (wv > 0.f) ? sv : -1e30f;
        }
    }
    __syncthreads();

    // ---- phase 2: masked softmax per row; 32 threads/row, interleaved (1-way banks). ----
    const int i2 = t >> 5, slot = t & 31;
    float m = -1e30f;
    #pragma unroll 8
    for (int jj = 0; jj < 32; ++jj) m = fmaxf(m, s_tile[i2][slot + 32 * jj]);
    #pragma unroll
    for (int off = 1; off < 32; off <<= 1) m = fmaxf(m, __shfl_xor(m, off));
    const unsigned short* wrow = wm + (i0 + i2) * NN;
    float sum = 0.f, aw = 0.f;
    #pragma unroll 4
    for (int jj = 0; jj < 32; ++jj) {
        const int j = slot + 32 * jj;
        const float sv = s_tile[i2][j];
        const float pv = (sv > -1e29f) ? __expf(sv - m) : 0.f;
        s_tile[i2][j] = pv;
        sum += pv;
        aw = fmaf(pv, fabsf(bf16_to_f32(wrow[j])), aw);
    }
    #pragma unroll
    for (int off = 1; off < 32; off <<= 1) {
        sum += __shfl_xor(sum, off);
        aw  += __shfl_xor(aw, off);
    }
    if (slot == 0) {
        const float inv = (m > -1e29f) ? 1.f / sum : 0.f;   // all-masked row -> 0
        inv_l[i2] = inv;
        aw_l[i2]  = aw * inv;
    }
    __syncthreads();

    // ---- phase 3: out[i][c] = inv * sum_j p[i][j] v[j][c]. thread = (i, jb, c4). ----
    const int i3 = t >> 5, jb = (t >> 2) & 7, c4 = t & 3;
    const float* vh = v + h * (NN * CH) + c4 * 4;
    float a0 = 0.f, a1 = 0.f, a2 = 0.f, a3 = 0.f;
    #pragma unroll 2
    for (int gg = 0; gg < 32; ++gg) {
        const int j0 = jb * 4 + 32 * gg;
        const float4 pp = *(const float4*)&s_tile[i3][j0];            // 128B contig across jb lanes
        const float4 v0 = *(const float4*)&vh[(j0 + 0) * CH];
        const float4 v1 = *(const float4*)&vh[(j0 + 1) * CH];
        const float4 v2 = *(const float4*)&vh[(j0 + 2) * CH];
        const float4 v3 = *(const float4*)&vh[(j0 + 3) * CH];
        a0 = fmaf(pp.x, v0.x, a0); a1 = fmaf(pp.x, v0.y, a1); a2 = fmaf(pp.x, v0.z, a2); a3 = fmaf(pp.x, v0.w, a3);
        a0 = fmaf(pp.y, v1.x, a0); a1 = fmaf(pp.y, v1.y, a1); a2 = fmaf(pp.y, v1.z, a2); a3 = fmaf(pp.y, v1.w, a3);
        a0 = fmaf(pp.z, v2.x, a0); a1 = fmaf(pp.z, v2.y, a1); a2 = fmaf(pp.z, v2.z, a2); a3 = fmaf(pp.z, v2.w, a3);
        a0 = fmaf(pp.w, v3.x, a0); a1 = fmaf(pp.w, v3.y, a1); a2 = fmaf(pp.w, v3.z, a2); a3 = fmaf(pp.w, v3.w, a3);
    }
    a0 += __shfl_xor(a0, 4); a0 += __shfl_xor(a0, 8); a0 += __shfl_xor(a0, 16);
    a1 += __shfl_xor(a1, 4); a1 += __shfl_xor(a1, 8); a1 += __shfl_xor(a1, 16);
    a2 += __shfl_xor(a2, 4); a2 += __shfl_xor(a2, 8); a2 += __shfl_xor(a2, 16);
    a3 += __shfl_xor(a3, 4); a3 += __shfl_xor(a3, 8); a3 += __shfl_xor(a3, 16);
    if (jb == 0) {
        const float inv = inv_l[i3], awv = aw_l[i3];
        const int idx = (i0 + i3) * HD + h * CH + c4 * 4;
        const float4 xo = *(const float4*)&x[idx];
        const float4 so = *(const float4*)&skip[idx];
        float4 o;
        o.x = xo.x + so.x + a0 * inv + awv * we_l[c4 * 4 + 0];
        o.y = xo.y + so.y + a1 * inv + awv * we_l[c4 * 4 + 1];
        o.z = xo.z + so.z + a2 * inv + awv * we_l[c4 * 4 + 2];
        o.w = xo.w + so.w + a3 * inv + awv * we_l[c4 * 4 + 3];
        *(float4*)&x[idx] = o;       // slice owned exclusively by this block
    }
}

// ---------------- launch ----------------
extern "C" void kernel_launch(void* const* d_in, const int* in_sizes, int n_in,
                              void* d_out, int out_size, void* d_ws, size_t ws_size,
                              hipStream_t stream) {
    const float* ent = (const float*)d_in[2];
    const float* W1  = (const float*)d_in[3];
    const float* b1  = (const float*)d_in[4];
    const float* W2  = (const float*)d_in[5];
    const float* b2  = (const float*)d_in[6];
    const float* Wq  = (const float*)d_in[7];
    const float* bq  = (const float*)d_in[8];
    const float* Wk  = (const float*)d_in[9];
    const float* bk  = (const float*)d_in[10];
    const float* Wv  = (const float*)d_in[11];
    const float* bv  = (const float*)d_in[12];
    const float* We  = (const float*)d_in[13];
    const float* Ws  = (const float*)d_in[14];
    const float* bs  = (const float*)d_in[15];

    unsigned short* wm = (unsigned short*)d_ws;   // [1024][1024] bf16, sign = mask (2 MB)
    float* fb = (float*)d_ws + (NN * NN / 2);     // float area after wm
    float* q  = fb;                               // [8][1024][16]  (reused as 'a' before layers)
    float* k  = q + NN * HD;                      //                (reused as 'b')
    float* v  = k + NN * HD;                      // [8][1024][16]
    float* sk = v + NN * HD;
    float* x  = (float*)d_out;                    // running entity state

    hipMemcpyAsync(x, ent, NN * HD * sizeof(float), hipMemcpyDeviceToDevice, stream);

    k_edge_ab<<<NN, 256, 0, stream>>>(ent, W1, b1, q /*a*/, k /*b*/);
    k_edge_w<<<dim3(32, 64), 256, 0, stream>>>(q, k, W2, b2, wm);

    for (int l = 0; l < NLAYERS; ++l) {
        k_proj<<<NN, 256, 0, stream>>>(x,
            Wq + l * HD * HD, bq + l * HD, Wk + l * HD * HD, bk + l * HD,
            Wv + l * HD * HD, bv + l * HD, Ws + l * HD * HD, bs + l * HD,
            q, k, v, sk);
        k_attn<<<dim3(NH, NN / TT), 256, 0, stream>>>(q, k, v, sk, wm, We + l * HD, x);
    }
}